// Round 6
// baseline (328.403 us; speedup 1.0000x reference)
//
#include <hip/hip_runtime.h>

// Problem constants
constexpr int B  = 64;
constexpr int U  = 512;
constexpr int AE = 1024;
constexpr int UE = 256;
constexpr int A  = 256;     // head size
constexpr int KQ = AE + UE; // 1280

typedef _Float16 f16x8 __attribute__((ext_vector_type(8)));
typedef _Float16 f16x4 __attribute__((ext_vector_type(4)));
typedef float    f32x4 __attribute__((ext_vector_type(4)));

// Baked position: logical k-chunk j of row u stored at chunk j^((u>>1)&3).
// R0's verified 2-way-free LDS swizzle, moved into the DATA so global->LDS
// copies are linear (global_load_lds writes base+lane*16 only).

// ---------------------------------------------------------------------------
// K0: build baked-linear 32-k-plane weight images (byte-identical to R3):
//   BTq [40][256][32] fp16, BTk [8][256][32] fp16
// value at [kp][row][pos] = W[k = kp*32 + ((pos>>3)^((row>>1)&3))*8 + (pos&7)][row]
// ---------------------------------------------------------------------------
__global__ void prep(const float* __restrict__ Wq, const float* __restrict__ Wk,
                     _Float16* __restrict__ BTq, _Float16* __restrict__ BTk) {
    int idx = blockIdx.x * 256 + threadIdx.x;
    const float* W;
    _Float16* Dst;
    int rem;
    if (idx < 40 * 256 * 32) { W = Wq; Dst = BTq; rem = idx; }
    else                     { W = Wk; Dst = BTk; rem = idx - 40 * 256 * 32; }
    int pos = rem & 31;
    int row = (rem >> 5) & 255;
    int kp  = rem >> 13;               // 32-k plane index
    int s = pos >> 3, e = pos & 7;
    int c = ((s ^ ((row >> 1) & 3)) << 3) | e;
    int k = kp * 32 + c;
    Dst[rem] = (_Float16)W[(size_t)k * 256 + row];
}

// ---------------------------------------------------------------------------
// K1/K2: C[m][n] = (concat A1|A2)[m][k] * B[k][n] + bias[n], fp16 out in
// permuted+baked layout [bb=row>>9][c5=col>>5][u=row&511][bakedpos(col&31,u)].
//
// R6 == R4 resubmit #2 (R4: container failed twice; R5: GPU acquisition
// timeout — both infra; kernel never executed. Audit held: no divergent
// barriers, satisfiable waits, all tail indices in bounds).
// 4-deep circular pipeline, BK=32. R0-R3 all drained vmcnt->0 every
// iteration => measured 9,700 cy/iter vs ~1,600 cy phase floor (bursty
// stop-and-go traffic; all pipes ~10%). Now: B staged 3 tiles ahead
// (global_load_lds, linear from baked image), A reg-loaded 2 ahead
// (ping-pong, static names), exactly ONE s_waitcnt vmcnt(5) per iter.
// FIFO at the wait: [B(t+1)ab@t-2, A(t+1)@t-1, B(t+2)ab@t-1, A(t+2)@t,
// B(t+3)ab@t] -> retiring to 5 guarantees A(t+1) (ds_write src) and the
// FIFO-earlier B(t+1) (next MFMA's operand), keeps ~2 iters of loads in
// flight. Unroll x4 for literal buffer ids; tail via index clamp (issue
// count stays uniform so the vmcnt arithmetic is exact; clamped loads
// land in already-consumed buffers). LDS 80 KB -> 2 blocks/CU.
// ---------------------------------------------------------------------------
__global__ __launch_bounds__(512) void gemm(
    const float* __restrict__ A1, int s1, int split,
    const float* __restrict__ A2, int s2,
    const _Float16* __restrict__ BT,   // baked-linear [nk][256][32] 32-k tiles
    const float* __restrict__ bias,    // [256]
    _Float16* __restrict__ Out,        // permuted+baked, see above
    int Ktot)
{
    __shared__ __align__(16) _Float16 Al[4][64][32];    // 16 KB
    __shared__ __align__(16) _Float16 Bl[4][256][32];   // 64 KB

    const int t    = threadIdx.x;
    const int lane = t & 63;
    const int l15  = lane & 15;
    const int w    = t >> 6;              // 0..7
    const int mbase = blockIdx.x * 64;

    const int wm = (w & 1) * 32;          // wave row base
    const int wn = (w >> 1) * 64;         // wave col base

    f32x4 acc[2][4] = {};

    // A staging: thread -> (row ar, 4-float k-chunk aq), one float4/tile
    const int ar = t >> 3;                // 0..63
    const int aq = t & 7;                 // 0..7
    const size_t grow = mbase + ar;
    const int nk = Ktot >> 5;             // 32-k tiles (40 or 8; both %4==0)

    auto loadA = [&](int kb, float4& dst) {
        int kk = kb < nk ? kb : nk - 1;   // clamp (redundant in-bounds read)
        int kg = kk * 32 + aq * 4;
        const float* src = (kg < split) ? (A1 + grow * (size_t)s1 + kg)
                                        : (A2 + grow * (size_t)s2 + (kg - split));
        dst = *(const float4*)src;
    };
    // B: 16-KB tile -> LDS, linear, 2 x global_load_lds(16B) per thread
    auto stageB = [&](int kb, int nb) {
        int kk = kb < nk ? kb : nk - 1;   // clamp (dead-buffer landing)
        const char* g = (const char*)BT + ((size_t)kk << 14) + (w << 10) + (lane << 4);
        char* l = (char*)(&Bl[nb][0][0]) + (w << 10) + (lane << 4);
        __builtin_amdgcn_global_load_lds(
            (const __attribute__((address_space(1))) void*)g,
            (__attribute__((address_space(3))) void*)l, 16, 0, 0);
        __builtin_amdgcn_global_load_lds(
            (const __attribute__((address_space(1))) void*)(g + 8192),
            (__attribute__((address_space(3))) void*)(l + 8192), 16, 0, 0);
    };
    auto writeA = [&](int nb, const float4& v) {
        f16x4 hv;
        hv[0] = (_Float16)v.x; hv[1] = (_Float16)v.y;
        hv[2] = (_Float16)v.z; hv[3] = (_Float16)v.w;
        *(f16x4*)(&Al[nb][ar][((aq >> 1) ^ ((ar >> 1) & 3)) * 8 + (aq & 1) * 4]) = hv;
    };
    const int rp = ((lane >> 4) ^ ((l15 >> 1) & 3)) * 8;  // swizzled read chunk
    auto mfmaStep = [&](int bc) {
        f16x8 af[2], bf[4];
        #pragma unroll
        for (int mt = 0; mt < 2; mt++)
            af[mt] = *(const f16x8*)(&Al[bc][wm + mt * 16 + l15][rp]);
        #pragma unroll
        for (int nt = 0; nt < 4; nt++)
            bf[nt] = *(const f16x8*)(&Bl[bc][wn + nt * 16 + l15][rp]);
        #pragma unroll
        for (int mt = 0; mt < 2; mt++)
            #pragma unroll
            for (int nt = 0; nt < 4; nt++)
                acc[mt][nt] = __builtin_amdgcn_mfma_f32_16x16x32_f16(
                    af[mt], bf[nt], acc[mt][nt], 0, 0, 0);
    };

    float4 aP0, aP1;   // static ping-pong (rule #20: no runtime-indexed reg arrays)

    // ---- prologue: FIFO = [A0, B0ab | B1ab, A1, B2ab], write A(0), retire B(0)
    loadA(0, aP0);
    stageB(0, 0);
    __builtin_amdgcn_sched_barrier(0);
    stageB(1, 1);
    loadA(1, aP1);
    stageB(2, 2);
    __builtin_amdgcn_sched_barrier(0);
    writeA(0, aP0);                       // compiler waits A0 (counted, B1/B2 keep flying)
    asm volatile("s_waitcnt vmcnt(5) lgkmcnt(0)" ::: "memory");  // retire B0ab
    __builtin_amdgcn_s_barrier();
    __builtin_amdgcn_sched_barrier(0);

    // ---- steady iteration: issue depth-2 A / depth-3 B, ONE counted wait
    auto iter = [&](int k, int bc, int bn1, int bn3, float4& aDst, float4& aSrc) {
        loadA(k + 2, aDst);               // A(k+2) -> regs
        stageB(k + 3, bn3);               // B(k+3) -> buf[(k+3)&3]
        __builtin_amdgcn_sched_barrier(0);
        mfmaStep(bc);                     // tile k (guaranteed by prev iter's wait)
        __builtin_amdgcn_sched_barrier(0);
        writeA(bn1, aSrc);                // A(k+1) cvt+ds_write -> buf[(k+1)&3]
        asm volatile("s_waitcnt vmcnt(5) lgkmcnt(0)" ::: "memory");
        __builtin_amdgcn_s_barrier();
        __builtin_amdgcn_sched_barrier(0);
    };

    for (int k4 = 0; k4 < nk; k4 += 4) {
        iter(k4 + 0, 0, 1, 3, aP0, aP1);
        iter(k4 + 1, 1, 2, 0, aP1, aP0);
        iter(k4 + 2, 2, 3, 1, aP0, aP1);
        iter(k4 + 3, 3, 0, 2, aP1, aP0);
    }
    asm volatile("s_waitcnt vmcnt(0)" ::: "memory");  // drain clamped leftovers

    // epilogue: C layout col=lane&15, row=(lane>>4)*4+reg; permuted+baked store
    const int col0 = wn + l15;
    const int rsub = (lane >> 4) * 4;
    #pragma unroll
    for (int nt = 0; nt < 4; nt++) {
        const int col = col0 + nt * 16;
        const float bv = bias[col];
        const int c5 = col >> 5, c31 = col & 31;
        const int sc = c31 >> 3, ei = c31 & 7;
        #pragma unroll
        for (int mt = 0; mt < 2; mt++)
            #pragma unroll
            for (int r = 0; r < 4; r++) {
                int row = mbase + wm + mt * 16 + rsub + r;
                int bb = row >> 9, u = row & 511;
                int posb = ((sc ^ ((u >> 1) & 3)) << 3) | ei;   // bake attn LDS swizzle
                Out[(((size_t)bb * 8 + c5) * 512 + u) * 32 + posb] =
                    (_Float16)(acc[mt][nt][r] + bv);
            }
    }
}

// ---------------------------------------------------------------------------
// K3: block = (batch, 64 q-rows), 512 thr / 8 waves. S = Qh Kh^T / 16 with
// multiplicative mask, row softmax entirely in registers + tiny LDS combine.
// K streamed in 8 chunks of 32 d via register-prefetch pipeline.
// (unchanged this round — gemm restructure attribution; attn is next target)
// ---------------------------------------------------------------------------
__global__ __launch_bounds__(512) void attn(
    const _Float16* __restrict__ Qh, const _Float16* __restrict__ Kh,
    const int* __restrict__ nr_own_units, const int* __restrict__ nr_units_enemy,
    const int* __restrict__ nr_own_flags, float* __restrict__ Out)
{
    __shared__ __align__(16) _Float16 Ql[8][64][32];   // 32 KB, 8 d-chunks
    __shared__ __align__(16) _Float16 Kl[512][32];     // 32 KB, one d-chunk
    __shared__ float red[64][4];                       // per-row cross-wave scratch

    const int t    = threadIdx.x;
    const int lane = t & 63;
    const int w    = t >> 6;                 // 0..7
    const int b    = blockIdx.y;
    const int qbase = blockIdx.x * 64;

    const int nf = nr_own_flags[b];
    const int nu = nr_own_units[b];
    const int ne = nr_units_enemy[b];

    const int wm = (w & 1) * 32;             // wave row base (0/32)
    const int wn = (w >> 1) * 128;           // wave col base (0..384)

    // ---- stage Q (once): linear copy of baked image
    f16x8 qreg[4];
    {
        const _Float16* Qb = Qh + ((size_t)b * 8 * 512 + qbase) * 32;
        #pragma unroll
        for (int j = 0; j < 4; j++) {
            int s = j * 512 + t;
            int p = s >> 8, row = (s & 255) >> 2, cq = s & 3;
            qreg[j] = *(const f16x8*)(Qb + ((size_t)p * 512 + row) * 32 + cq * 8);
        }
        #pragma unroll
        for (int j = 0; j < 4; j++) {
            int s = j * 512 + t;
            int p = s >> 8, row = (s & 255) >> 2, cq = s & 3;
            *(f16x8*)(&Ql[p][row][cq * 8]) = qreg[j];   // linear (swizzle baked)
        }
    }

    // ---- K chunk staging mapping: s = j*512 + t -> row = s>>2, cq = s&3
    const _Float16* Kb = Kh + (size_t)b * 8 * 512 * 32;
    f16x8 kreg[4];
    const int krow = t >> 2;                 // + j*128
    const int kq   = t & 3;
    auto loadK = [&](int c) {
        const _Float16* Kc = Kb + (size_t)c * 512 * 32;
        #pragma unroll
        for (int j = 0; j < 4; j++)
            kreg[j] = *(const f16x8*)(Kc + ((size_t)(j * 128 + krow)) * 32 + kq * 8);
    };
    loadK(0);

    f32x4 acc[2][8] = {};
    const int rsw = (((lane & 15) >> 1) & 3);
    for (int c = 0; c < 8; c++) {
        __syncthreads();   // c==0: publish Ql; else: prev Kl readers done
        #pragma unroll
        for (int j = 0; j < 4; j++) {
            int row = j * 128 + krow;
            *(f16x8*)(&Kl[row][kq * 8]) = kreg[j];      // linear (swizzle baked)
        }
        __syncthreads();
        if (c < 7) loadK(c + 1);
        f16x8 af[2], bf[8];
        #pragma unroll
        for (int mt = 0; mt < 2; mt++)
            af[mt] = *(const f16x8*)(&Ql[c][wm + mt * 16 + (lane & 15)][((lane >> 4) ^ rsw) * 8]);
        #pragma unroll
        for (int nt = 0; nt < 8; nt++)
            bf[nt] = *(const f16x8*)(&Kl[wn + nt * 16 + (lane & 15)][((lane >> 4) ^ rsw) * 8]);
        #pragma unroll
        for (int mt = 0; mt < 2; mt++)
            #pragma unroll
            for (int nt = 0; nt < 8; nt++)
                acc[mt][nt] = __builtin_amdgcn_mfma_f32_16x16x32_f16(
                    af[mt], bf[nt], acc[mt][nt], 0, 0, 0);
    }

    // ---- mask + scale in registers
    const int rsub = (lane >> 4) * 4;
    #pragma unroll
    for (int mt = 0; mt < 2; mt++)
        #pragma unroll
        for (int nt = 0; nt < 8; nt++)
            #pragma unroll
            for (int r = 0; r < 4; r++) {
                int rl = wm + mt * 16 + rsub + r;
                int uq = qbase + rl;
                int col = wn + nt * 16 + (lane & 15);
                bool ok = (col < ne) && (uq >= nf) && (uq < nu);
                acc[mt][nt][r] = acc[mt][nt][r] * 0.0625f * (ok ? 1.0f : 1e-9f);
            }

    // ---- row max: over nt in-lane, then across 16-lane group, then cross-wave
    float mx[2][4];
    #pragma unroll
    for (int mt = 0; mt < 2; mt++)
        #pragma unroll
        for (int r = 0; r < 4; r++) {
            float m = acc[mt][0][r];
            #pragma unroll
            for (int nt = 1; nt < 8; nt++) m = fmaxf(m, acc[mt][nt][r]);
            #pragma unroll
            for (int off = 1; off <= 8; off <<= 1) m = fmaxf(m, __shfl_xor(m, off));
            mx[mt][r] = m;
        }
    if ((lane & 15) == 0) {
        #pragma unroll
        for (int mt = 0; mt < 2; mt++)
            #pragma unroll
            for (int r = 0; r < 4; r++)
                red[wm + mt * 16 + rsub + r][w >> 1] = mx[mt][r];
    }
    __syncthreads();
    #pragma unroll
    for (int mt = 0; mt < 2; mt++)
        #pragma unroll
        for (int r = 0; r < 4; r++) {
            f32x4 v = *(const f32x4*)(&red[wm + mt * 16 + rsub + r][0]);
            mx[mt][r] = fmaxf(fmaxf(v[0], v[1]), fmaxf(v[2], v[3]));
        }
    __syncthreads();   // everyone read max before red is reused for sums

    // ---- exp + row sum
    float sm[2][4];
    #pragma unroll
    for (int mt = 0; mt < 2; mt++)
        #pragma unroll
        for (int r = 0; r < 4; r++) {
            float s = 0.f;
            #pragma unroll
            for (int nt = 0; nt < 8; nt++) {
                float e = __expf(acc[mt][nt][r] - mx[mt][r]);
                acc[mt][nt][r] = e;
                s += e;
            }
            #pragma unroll
            for (int off = 1; off <= 8; off <<= 1) s += __shfl_xor(s, off);
            sm[mt][r] = s;
        }
    if ((lane & 15) == 0) {
        #pragma unroll
        for (int mt = 0; mt < 2; mt++)
            #pragma unroll
            for (int r = 0; r < 4; r++)
                red[wm + mt * 16 + rsub + r][w >> 1] = sm[mt][r];
    }
    __syncthreads();

    // ---- normalize + store
    #pragma unroll
    for (int mt = 0; mt < 2; mt++)
        #pragma unroll
        for (int r = 0; r < 4; r++) {
            int rl = wm + mt * 16 + rsub + r;
            f32x4 v = *(const f32x4*)(&red[rl][0]);
            float inv = 1.0f / (v[0] + v[1] + v[2] + v[3]);
            float* orow = Out + ((size_t)b * 512 + qbase + rl) * 512 + wn + (lane & 15);
            #pragma unroll
            for (int nt = 0; nt < 8; nt++)
                orow[nt * 16] = acc[mt][nt][r] * inv;
        }
}

// ---------------------------------------------------------------------------
extern "C" void kernel_launch(void* const* d_in, const int* in_sizes, int n_in,
                              void* d_out, int out_size, void* d_ws, size_t ws_size,
                              hipStream_t stream) {
    const float* ar    = (const float*)d_in[0];   // [B,U,AE]
    const float* own   = (const float*)d_in[1];   // [B,U,UE]
    const float* enemy = (const float*)d_in[2];   // [B,U,UE]
    const int*   n_own   = (const int*)d_in[3];   // nr_own_units
    const int*   n_enemy = (const int*)d_in[4];   // nr_units_enemy
    const int*   n_flags = (const int*)d_in[5];   // nr_own_flags
    const float* Wq = (const float*)d_in[6];
    const float* bq = (const float*)d_in[7];
    const float* Wk = (const float*)d_in[8];
    const float* bk = (const float*)d_in[9];
    float* out = (float*)d_out;

    char* ws = (char*)d_ws;
    _Float16* BTq = (_Float16*)(ws);                       // 40*16384 B = 655360 B
    _Float16* BTk = (_Float16*)(ws + 655360);              // 8*16384 B  = 131072 B
    _Float16* Qh  = (_Float16*)(ws + 786432);              // [64][8][512][32] f16
    _Float16* Kh  = (_Float16*)(ws + 786432 + 16777216);   // [64][8][512][32] f16

    // 48 planes total (Q:40, K:8) * 256*32 elems = 393216 -> 1536 blocks
    prep<<<dim3(1536), dim3(256), 0, stream>>>(Wq, Wk, BTq, BTk);

    // Q = concat(ar, own) @ Wq + bq   (BM=64 -> grid 512, nk=40)
    gemm<<<dim3(512), dim3(512), 0, stream>>>(ar, AE, AE, own, UE, BTq, bq, Qh, KQ);
    // K = enemy @ Wk + bk  (split=0 -> always A2 path, nk=8)
    gemm<<<dim3(512), dim3(512), 0, stream>>>(enemy, UE, 0, enemy, UE, BTk, bk, Kh, A);

    attn<<<dim3(8, B), dim3(512), 0, stream>>>(Qh, Kh, n_own, n_enemy, n_flags, out);
}